// Round 11
// baseline (626.220 us; speedup 1.0000x reference)
//
#include <hip/hip_runtime.h>

#define HDIM 64
#define CAP_M 96
#define CAP_U 32
#define OVF_MAX 65536

// ---------------- bf16 helpers ----------------
__device__ __forceinline__ float bf2f(unsigned short u) {
  unsigned int x = ((unsigned int)u) << 16;
  return __uint_as_float(x);
}
__device__ __forceinline__ unsigned short f2bf(float f) {
  unsigned int x = __float_as_uint(f);
  unsigned int r = (x + 0x7FFFu + ((x >> 16) & 1u)) >> 16;  // RNE
  return (unsigned short)r;
}

// ---------------- zero (must precede fill atomics -> own dispatch) ----------------
__global__ void k_zero1(int* __restrict__ a, int n) {
  int i = blockIdx.x * blockDim.x + threadIdx.x;
  int stride = gridDim.x * blockDim.x;
  for (int j = i; j < n; j += stride) a[j] = 0;
}

// ---------------- fused fill + table-convert ----------------
// bid%16 < 8  -> fill block, class xg = bid&7 (= bid%16, preserves the
//                bid%8<->XCD store-locality heuristic), rank = bid>>4 (256/class)
// bid%16 >= 8 -> streaming fp32->bf16 convert block (2048 virtual blocks)
// Fill is atomic-queue-bound (VALU 4.6%, HBM 20%) so convert work rides on
// idle VALU/BW of co-resident CUs. Atomic cost ~45ns/op device-wide
// regardless of locality/scope (measured r4-r8) -> only COUNT matters (4M).
__global__ __launch_bounds__(256) void k_fill_conv(const int* __restrict__ srcU,
                                                   const int* __restrict__ dstM,
                                                   int* __restrict__ curM,
                                                   int* __restrict__ bktM,
                                                   int* __restrict__ ovfM_cnt,
                                                   int* __restrict__ ovfM,
                                                   int* __restrict__ curU,
                                                   int* __restrict__ bktU,
                                                   int* __restrict__ ovfU_cnt,
                                                   int* __restrict__ ovfU,
                                                   int E, int NM_, int NU_,
                                                   const float* __restrict__ ut,
                                                   unsigned short* __restrict__ ub, int n8u,
                                                   const float* __restrict__ mt,
                                                   unsigned short* __restrict__ mb, int n8m) {
  int w16 = blockIdx.x & 15;
  int t = threadIdx.x;
  if (w16 >= 8) {
    // ---- convert class ----
    int cid = (blockIdx.x >> 4) * 8 + (w16 - 8);
    int nconv = (gridDim.x >> 4) * 8;
    int stride = nconv * 256;
    for (int j = cid * 256 + t; j < n8u; j += stride) {
      const float4* p = (const float4*)(ut + (size_t)j * 8);
      float4 a = p[0], b = p[1];
      uint4 o;
      o.x = (unsigned int)f2bf(a.x) | ((unsigned int)f2bf(a.y) << 16);
      o.y = (unsigned int)f2bf(a.z) | ((unsigned int)f2bf(a.w) << 16);
      o.z = (unsigned int)f2bf(b.x) | ((unsigned int)f2bf(b.y) << 16);
      o.w = (unsigned int)f2bf(b.z) | ((unsigned int)f2bf(b.w) << 16);
      *(uint4*)(ub + (size_t)j * 8) = o;
    }
    for (int j = cid * 256 + t; j < n8m; j += stride) {
      const float4* p = (const float4*)(mt + (size_t)j * 8);
      float4 a = p[0], b = p[1];
      uint4 o;
      o.x = (unsigned int)f2bf(a.x) | ((unsigned int)f2bf(a.y) << 16);
      o.y = (unsigned int)f2bf(a.z) | ((unsigned int)f2bf(a.w) << 16);
      o.z = (unsigned int)f2bf(b.x) | ((unsigned int)f2bf(b.y) << 16);
      o.w = (unsigned int)f2bf(b.z) | ((unsigned int)f2bf(b.w) << 16);
      *(uint4*)(mb + (size_t)j * 8) = o;
    }
    return;
  }
  // ---- fill class ----
  int xg = w16;  // == blockIdx.x & 7
  int mlo = (int)(((long long)NM_ * xg) >> 3);
  int mhi = (xg == 7) ? NM_ : (int)(((long long)NM_ * (xg + 1)) >> 3);
  int ulo = (int)(((long long)NU_ * xg) >> 3);
  int uhi = (xg == 7) ? NU_ : (int)(((long long)NU_ * (xg + 1)) >> 3);
  int li = (blockIdx.x >> 4) * 256 + t;
  int stride = (gridDim.x >> 4) * 256;
  int E4 = E >> 2;
  const int4* s4 = (const int4*)srcU;
  const int4* d4 = (const int4*)dstM;
  for (int e = li; e < E4; e += stride) {
    int4 d = d4[e];
    int4 s = s4[e];
#pragma unroll
    for (int k = 0; k < 4; ++k) {
      int dd = (k == 0) ? d.x : (k == 1) ? d.y : (k == 2) ? d.z : d.w;
      int ss = (k == 0) ? s.x : (k == 1) ? s.y : (k == 2) ? s.z : s.w;
      if (dd >= mlo && dd < mhi) {
        int p = atomicAdd(&curM[dd], 1);
        if (p < CAP_M) bktM[(size_t)dd * CAP_M + p] = ss;
        else { int q = atomicAdd(ovfM_cnt, 1); if (q < OVF_MAX) { ovfM[2 * q] = dd; ovfM[2 * q + 1] = ss; } }
      }
      if (ss >= ulo && ss < uhi) {
        int p = atomicAdd(&curU[ss], 1);
        if (p < CAP_U) bktU[(size_t)ss * CAP_U + p] = dd;
        else { int q = atomicAdd(ovfU_cnt, 1); if (q < OVF_MAX) { ovfU[2 * q] = ss; ovfU[2 * q + 1] = dd; } }
      }
    }
  }
  for (int e = E4 * 4 + li; e < E; e += stride) {
    int dd = dstM[e];
    int ss = srcU[e];
    if (dd >= mlo && dd < mhi) {
      int p = atomicAdd(&curM[dd], 1);
      if (p < CAP_M) bktM[(size_t)dd * CAP_M + p] = ss;
      else { int q = atomicAdd(ovfM_cnt, 1); if (q < OVF_MAX) { ovfM[2 * q] = dd; ovfM[2 * q + 1] = ss; } }
    }
    if (ss >= ulo && ss < uhi) {
      int p = atomicAdd(&curU[ss], 1);
      if (p < CAP_U) bktU[(size_t)ss * CAP_U + p] = dd;
      else { int q = atomicAdd(ovfU_cnt, 1); if (q < OVF_MAX) { ovfU[2 * q] = ss; ovfU[2 * q + 1] = dd; } }
    }
  }
}

// ---------------- aggregation: 8 lanes/node, 16B loads, bf16-STRIDED output ----------------
// Output row slot = 256 B (fp32 stride); bf16 mean occupies first 128 B.
// Keeps layer-2 xform's in-place row aliasing exact while halving agg traffic.
__device__ __forceinline__ void acc8(float4& a, float4& b, uint4 w) {
  a.x += __uint_as_float(w.x << 16);
  a.y += __uint_as_float(w.x & 0xFFFF0000u);
  a.z += __uint_as_float(w.y << 16);
  a.w += __uint_as_float(w.y & 0xFFFF0000u);
  b.x += __uint_as_float(w.z << 16);
  b.y += __uint_as_float(w.z & 0xFFFF0000u);
  b.z += __uint_as_float(w.w << 16);
  b.w += __uint_as_float(w.w & 0xFFFF0000u);
}

__global__ __launch_bounds__(256) void k_agg8(const unsigned short* __restrict__ xb,
                                              const int* __restrict__ cur,
                                              const int* __restrict__ bkt,
                                              int cap,
                                              void* __restrict__ aggv,   // strided bf16
                                              int n_dst) {
  int t = threadIdx.x;
  int q = t & 7;                        // col octet: cols 8q..8q+7
  int gg = (blockIdx.x * 256 + t) >> 3; // node
  int stride = (gridDim.x * 256) >> 3;
  char* aggc = (char*)aggv;

  for (int node = gg; node < n_dst; node += stride) {
    int deg = cur[node];
    int nb = deg < cap ? deg : cap;
    const int* lst = bkt + (size_t)node * cap;
    float4 a = make_float4(0.f, 0.f, 0.f, 0.f);
    float4 b = a;
    int e = 0;
    for (; e + 4 <= nb; e += 4) {
      int4 ia = *(const int4*)&lst[e];   // same addr across 8 lanes -> broadcast
      uint4 w0 = *(const uint4*)&xb[(size_t)ia.x * HDIM + 8 * q];
      uint4 w1 = *(const uint4*)&xb[(size_t)ia.y * HDIM + 8 * q];
      uint4 w2 = *(const uint4*)&xb[(size_t)ia.z * HDIM + 8 * q];
      uint4 w3 = *(const uint4*)&xb[(size_t)ia.w * HDIM + 8 * q];
      acc8(a, b, w0);
      acc8(a, b, w1);
      acc8(a, b, w2);
      acc8(a, b, w3);
    }
    for (; e < nb; ++e) {
      uint4 w0 = *(const uint4*)&xb[(size_t)lst[e] * HDIM + 8 * q];
      acc8(a, b, w0);
    }
    float inv = deg > 0 ? 1.f / (float)deg : 0.f;
    uint4 o;
    o.x = (unsigned int)f2bf(a.x * inv) | ((unsigned int)f2bf(a.y * inv) << 16);
    o.y = (unsigned int)f2bf(a.z * inv) | ((unsigned int)f2bf(a.w * inv) << 16);
    o.z = (unsigned int)f2bf(b.x * inv) | ((unsigned int)f2bf(b.y * inv) << 16);
    o.w = (unsigned int)f2bf(b.z * inv) | ((unsigned int)f2bf(b.w * inv) << 16);
    *(uint4*)(aggc + (size_t)node * 256 + 16 * q) = o;
  }
}

// ---------------- overflow fixup: CAS add into strided bf16 agg (cold path) ----------------
__device__ __forceinline__ void cas_add_bf2(unsigned int* p, float d0, float d1) {
  unsigned int old = *p;
  for (;;) {
    unsigned int assumed = old;
    float e0 = __uint_as_float(assumed << 16) + d0;
    float e1 = __uint_as_float(assumed & 0xFFFF0000u) + d1;
    unsigned int nv = (unsigned int)f2bf(e0) | ((unsigned int)f2bf(e1) << 16);
    old = atomicCAS(p, assumed, nv);
    if (old == assumed) break;
  }
}

__device__ __forceinline__ void fix_body(const int* __restrict__ cnt_p,
                                         const int* __restrict__ ovf,
                                         const unsigned short* __restrict__ xb,
                                         const int* __restrict__ cur,
                                         void* __restrict__ aggv,
                                         int bid, int nblk) {
  int n = *cnt_p;
  if (n > OVF_MAX) n = OVF_MAX;
  char* aggc = (char*)aggv;
  int tid = bid * 256 + threadIdx.x;
  int q = tid & 15;
  int p = tid >> 4;
  int stride = (nblk * 256) >> 4;
  for (; p < n; p += stride) {
    int d = ovf[2 * p];
    int s = ovf[2 * p + 1];
    float inv = 1.f / (float)cur[d];
    ushort4 v = *(const ushort4*)&xb[(size_t)s * HDIM + 4 * q];
    unsigned int* w = (unsigned int*)(aggc + (size_t)d * 256 + 8 * q);
    cas_add_bf2(w + 0, bf2f(v.x) * inv, bf2f(v.y) * inv);
    cas_add_bf2(w + 1, bf2f(v.z) * inv, bf2f(v.w) * inv);
  }
}

__global__ __launch_bounds__(256) void k_fix2(const int* __restrict__ cntM,
                                              const int* __restrict__ ovfM,
                                              const unsigned short* __restrict__ xbM,
                                              const int* __restrict__ curM,
                                              void* __restrict__ aggM,
                                              const int* __restrict__ cntU,
                                              const int* __restrict__ ovfU,
                                              const unsigned short* __restrict__ xbU,
                                              const int* __restrict__ curU,
                                              void* __restrict__ aggU) {
  if (blockIdx.x < 16) fix_body(cntM, ovfM, xbM, curM, aggM, blockIdx.x, 16);
  else                 fix_body(cntU, ovfU, xbU, curU, aggU, blockIdx.x - 16, 16);
}

// component select with compile-time c (folds under #pragma unroll)
__device__ __forceinline__ float f4c(const float4& v, int c) {
  return c == 0 ? v.x : c == 1 ? v.y : c == 2 ? v.z : v.w;
}

// ---------------- transform: out = A@Wl + X@Wr + b (opt relu) ----------------
// A is bf16 at 256B row stride (agg output). X is dense bf16.
// X/out (and A/out) may ALIAS (exact same-row in-place; wave lockstep makes
// all row loads complete before any lane's store). OUTBF: bf16 dense out.
template <int OUTBF>
__global__ __launch_bounds__(256) void k_xform(const void* A,
                                               const unsigned short* X,
                                               const float* __restrict__ Wl,
                                               const float* __restrict__ Wr,
                                               const float* __restrict__ bias,
                                               void* outv,
                                               int n_dst, int do_relu) {
  __shared__ float sW[2 * HDIM * HDIM];    // Wl | Wr, 32 KB
  __shared__ float sAX[4][2][8][HDIM];     // [wave][a|x][slot][col], 16 KB

  int t = threadIdx.x;
  {
    const float4* wl4 = (const float4*)Wl;
    const float4* wr4 = (const float4*)Wr;
    float4* s4 = (float4*)sW;
    for (int i = t; i < HDIM * HDIM / 4; i += 256) {
      s4[i] = wl4[i];
      s4[HDIM * HDIM / 4 + i] = wr4[i];
    }
  }
  __syncthreads();

  int lane = t & 63;
  int w = t >> 6;
  int q = lane & 15;
  int g = lane >> 4;
  float4 bj = *(const float4*)&bias[4 * q];
  const unsigned short* Ab = (const unsigned short*)A;  // strided: row i at ushort idx i*128

  int wid = blockIdx.x * 4 + w;
  int nw = gridDim.x * 4;

  for (int base = 8 * wid; base < n_dst; base += 8 * nw) {
    int na = base + g;
    int nb = base + 4 + g;
    float4 z = make_float4(0.f, 0.f, 0.f, 0.f);
    float4 aA = z, xA = z, aB = z, xB = z;
    if (na < n_dst) {
      ushort4 va = *(const ushort4*)&Ab[(size_t)na * 128 + 4 * q];
      aA = make_float4(bf2f(va.x), bf2f(va.y), bf2f(va.z), bf2f(va.w));
      ushort4 v = *(const ushort4*)&X[(size_t)na * HDIM + 4 * q];
      xA = make_float4(bf2f(v.x), bf2f(v.y), bf2f(v.z), bf2f(v.w));
    }
    if (nb < n_dst) {
      ushort4 va = *(const ushort4*)&Ab[(size_t)nb * 128 + 4 * q];
      aB = make_float4(bf2f(va.x), bf2f(va.y), bf2f(va.z), bf2f(va.w));
      ushort4 v = *(const ushort4*)&X[(size_t)nb * HDIM + 4 * q];
      xB = make_float4(bf2f(v.x), bf2f(v.y), bf2f(v.z), bf2f(v.w));
    }
    *(float4*)&sAX[w][0][g][4 * q] = aA;
    *(float4*)&sAX[w][1][g][4 * q] = xA;
    *(float4*)&sAX[w][0][4 + g][4 * q] = aB;
    *(float4*)&sAX[w][1][4 + g][4 * q] = xB;

    float4 o[8];
#pragma unroll
    for (int s = 0; s < 8; ++s) o[s] = z;

#pragma unroll
    for (int hq = 0; hq < 4; ++hq) {
      int hbase = 16 * g + 4 * hq;
      float4 wl[4], wr[4];
#pragma unroll
      for (int c = 0; c < 4; ++c) {
        wl[c] = *(const float4*)&sW[(hbase + c) * HDIM + 4 * q];
        wr[c] = *(const float4*)&sW[HDIM * HDIM + (hbase + c) * HDIM + 4 * q];
      }
#pragma unroll
      for (int s = 0; s < 8; ++s) {
        float4 av = *(const float4*)&sAX[w][0][s][hbase];
        float4 xv = *(const float4*)&sAX[w][1][s][hbase];
#pragma unroll
        for (int c = 0; c < 4; ++c) {
          float a1 = f4c(av, c), x1 = f4c(xv, c);
          o[s].x += a1 * wl[c].x + x1 * wr[c].x;
          o[s].y += a1 * wl[c].y + x1 * wr[c].y;
          o[s].z += a1 * wl[c].z + x1 * wr[c].z;
          o[s].w += a1 * wl[c].w + x1 * wr[c].w;
        }
      }
    }

#pragma unroll
    for (int m = 16; m <= 32; m <<= 1) {
#pragma unroll
      for (int s = 0; s < 8; ++s) {
        o[s].x += __shfl_xor(o[s].x, m);
        o[s].y += __shfl_xor(o[s].y, m);
        o[s].z += __shfl_xor(o[s].z, m);
        o[s].w += __shfl_xor(o[s].w, m);
      }
    }

    float4 s0, s1;
    if (g == 0)      { s0 = o[0]; s1 = o[1]; }
    else if (g == 1) { s0 = o[2]; s1 = o[3]; }
    else if (g == 2) { s0 = o[4]; s1 = o[5]; }
    else             { s0 = o[6]; s1 = o[7]; }
    int n0 = base + 2 * g;
    int n1 = base + 2 * g + 1;
    s0.x += bj.x; s0.y += bj.y; s0.z += bj.z; s0.w += bj.w;
    s1.x += bj.x; s1.y += bj.y; s1.z += bj.z; s1.w += bj.w;
    if (do_relu) {
      s0.x = fmaxf(s0.x, 0.f); s0.y = fmaxf(s0.y, 0.f);
      s0.z = fmaxf(s0.z, 0.f); s0.w = fmaxf(s0.w, 0.f);
      s1.x = fmaxf(s1.x, 0.f); s1.y = fmaxf(s1.y, 0.f);
      s1.z = fmaxf(s1.z, 0.f); s1.w = fmaxf(s1.w, 0.f);
    }
    if (OUTBF) {
      unsigned short* ob = (unsigned short*)outv;
      if (n0 < n_dst) {
        ushort4 r = make_ushort4(f2bf(s0.x), f2bf(s0.y), f2bf(s0.z), f2bf(s0.w));
        *(ushort4*)&ob[(size_t)n0 * HDIM + 4 * q] = r;
      }
      if (n1 < n_dst) {
        ushort4 r = make_ushort4(f2bf(s1.x), f2bf(s1.y), f2bf(s1.z), f2bf(s1.w));
        *(ushort4*)&ob[(size_t)n1 * HDIM + 4 * q] = r;
      }
    } else {
      float* of = (float*)outv;
      if (n0 < n_dst) *(float4*)&of[(size_t)n0 * HDIM + 4 * q] = s0;
      if (n1 < n_dst) *(float4*)&of[(size_t)n1 * HDIM + 4 * q] = s1;
    }
  }
}

// ---------------- launch ----------------

static inline int imin(int a, int b) { return a < b ? a : b; }

extern "C" void kernel_launch(void* const* d_in, const int* in_sizes, int n_in,
                              void* d_out, int out_size, void* d_ws, size_t ws_size,
                              hipStream_t stream) {
  const int NU = in_sizes[0];
  const int NM = in_sizes[1];
  const int E  = in_sizes[2];

  const int* src_um = (const int*)d_in[2];
  const int* dst_um = (const int*)d_in[3];
  const float* user_table  = (const float*)d_in[6];
  const float* movie_table = (const float*)d_in[7];
  const float* Wl1_um = (const float*)d_in[8];
  const float* Wr1_um = (const float*)d_in[9];
  const float* Wl1_mu = (const float*)d_in[10];
  const float* Wr1_mu = (const float*)d_in[11];
  const float* Wl2_um = (const float*)d_in[12];
  const float* Wr2_um = (const float*)d_in[13];
  const float* Wl2_mu = (const float*)d_in[14];
  const float* Wr2_mu = (const float*)d_in[15];
  const float* b1_um = (const float*)d_in[16];
  const float* b1_mu = (const float*)d_in[17];
  const float* b2_um = (const float*)d_in[18];
  const float* b2_mu = (const float*)d_in[19];

  float* out_u2 = (float*)d_out;                       // [NU,64]
  float* out_m2 = (float*)d_out + (size_t)NU * HDIM;   // [NM,64]
  // strided-bf16 agg scratch aliases the fp32 output rows (same 256B slots);
  // layer-2 xform reads row i (bf16, first 128B) then writes row i (fp32).
  void* aggu = (void*)out_u2;
  void* aggm = (void*)out_m2;

  // workspace carve (256B aligned); total ~73.7 MB
  char* ws = (char*)d_ws;
  size_t off = 0;
  auto carve = [&](size_t bytes) -> char* {
    char* p = ws + off;
    off = (off + bytes + 255) & ~(size_t)255;
    return p;
  };
  int* meta = (int*)carve((size_t)(NM + NU + 2) * 4);
  int* curm = meta;
  int* curu = meta + NM;
  int* ovfm_cnt = meta + NM + NU;
  int* ovfu_cnt = meta + NM + NU + 1;
  int nmeta = NM + NU + 2;
  int* ovfm = (int*)carve((size_t)OVF_MAX * 2 * 4);
  int* ovfu = (int*)carve((size_t)OVF_MAX * 2 * 4);
  int* bktm = (int*)carve((size_t)NM * CAP_M * 4);   // users bucketed by movie
  int* bktu = (int*)carve((size_t)NU * CAP_U * 4);   // movies bucketed by user
  unsigned short* mb = (unsigned short*)carve((size_t)NM * HDIM * 2);  // bf16 movie tbl -> m1
  unsigned short* ub = (unsigned short*)carve((size_t)NU * HDIM * 2);  // bf16 user tbl -> u1
  (void)ws_size;

  const int TB = 256;

  // 0) zero counters (must complete before fill atomics)
  k_zero1<<<256, TB, 0, stream>>>(meta, nmeta);

  // 1) fused fill + table converts (16-block interleave for co-residency)
  int n8u = NU * HDIM / 8, n8m = NM * HDIM / 8;
  k_fill_conv<<<4096, TB, 0, stream>>>(src_um, dst_um,
                                       curm, bktm, ovfm_cnt, ovfm,
                                       curu, bktu, ovfu_cnt, ovfu,
                                       E, NM, NU,
                                       user_table, ub, n8u,
                                       movie_table, mb, n8m);

  // agg grids: 8 lanes/node -> 32 nodes/block
  int gAm = imin((NM + 31) / 32, 8192);
  int gAu = imin((NU + 31) / 32, 8192);
  int gXm = imin((NM + 31) / 32, 1024);
  int gXu = imin((NU + 31) / 32, 1024);

  // 2) layer 1 (relu): SERIAL aggs (r9 cache-mixing lesson), fix, serial xforms
  k_agg8<<<gAm, TB, 0, stream>>>(ub, curm, bktm, CAP_M, aggm, NM);
  k_agg8<<<gAu, TB, 0, stream>>>(mb, curu, bktu, CAP_U, aggu, NU);
  k_fix2<<<32, TB, 0, stream>>>(ovfm_cnt, ovfm, ub, curm, aggm,
                                ovfu_cnt, ovfu, mb, curu, aggu);
  k_xform<1><<<gXm, TB, 0, stream>>>(aggm, mb, Wl1_um, Wr1_um, b1_um,
                                     mb, NM, 1);   // mb becomes m1 (bf16)
  k_xform<1><<<gXu, TB, 0, stream>>>(aggu, ub, Wl1_mu, Wr1_mu, b1_mu,
                                     ub, NU, 1);   // ub becomes u1 (bf16)

  // 3) layer 2 (no relu): aggs into d_out slots, xform in-place -> fp32 out
  k_agg8<<<gAm, TB, 0, stream>>>(ub, curm, bktm, CAP_M, aggm, NM);
  k_agg8<<<gAu, TB, 0, stream>>>(mb, curu, bktu, CAP_U, aggu, NU);
  k_fix2<<<32, TB, 0, stream>>>(ovfm_cnt, ovfm, ub, curm, aggm,
                                ovfu_cnt, ovfu, mb, curu, aggu);
  k_xform<0><<<gXm, TB, 0, stream>>>(aggm, mb, Wl2_um, Wr2_um, b2_um,
                                     out_m2, NM, 0);
  k_xform<0><<<gXu, TB, 0, stream>>>(aggu, ub, Wl2_mu, Wr2_mu, b2_mu,
                                     out_u2, NU, 0);
}

// Round 12
// 523.192 us; speedup vs baseline: 1.1969x; 1.1969x over previous
//
#include <hip/hip_runtime.h>

#define HDIM 64
#define CAP_M 96
#define CAP_U 32
#define OVF_MAX 65536

// ---------------- bf16 helpers ----------------
__device__ __forceinline__ float bf2f(unsigned short u) {
  unsigned int x = ((unsigned int)u) << 16;
  return __uint_as_float(x);
}
__device__ __forceinline__ unsigned short f2bf(float f) {
  unsigned int x = __float_as_uint(f);
  unsigned int r = (x + 0x7FFFu + ((x >> 16) & 1u)) >> 16;  // RNE
  return (unsigned short)r;
}

// ---------------- init: zero meta + bf16 table copies (one dispatch) ----------------
// Pure streaming (no gathers) -> safe to fuse (r9 lesson: never mix gather regimes).
__global__ __launch_bounds__(256) void k_init(int* __restrict__ meta, int nmeta,
                                              const float* __restrict__ ut,
                                              unsigned short* __restrict__ ub, int n8u,
                                              const float* __restrict__ mt,
                                              unsigned short* __restrict__ mb, int n8m) {
  int bid = blockIdx.x;
  if (bid < 512) {
    int i = bid * 256 + threadIdx.x;
    for (int j = i; j < nmeta; j += 512 * 256) meta[j] = 0;
  } else if (bid < 512 + 2048) {
    int i = (bid - 512) * 256 + threadIdx.x;
    for (int j = i; j < n8u; j += 2048 * 256) {
      const float4* p = (const float4*)(ut + (size_t)j * 8);
      float4 a = p[0], b = p[1];
      uint4 o;
      o.x = (unsigned int)f2bf(a.x) | ((unsigned int)f2bf(a.y) << 16);
      o.y = (unsigned int)f2bf(a.z) | ((unsigned int)f2bf(a.w) << 16);
      o.z = (unsigned int)f2bf(b.x) | ((unsigned int)f2bf(b.y) << 16);
      o.w = (unsigned int)f2bf(b.z) | ((unsigned int)f2bf(b.w) << 16);
      *(uint4*)(ub + (size_t)j * 8) = o;
    }
  } else {
    int i = (bid - 512 - 2048) * 256 + threadIdx.x;
    for (int j = i; j < n8m; j += 512 * 256) {
      const float4* p = (const float4*)(mt + (size_t)j * 8);
      float4 a = p[0], b = p[1];
      uint4 o;
      o.x = (unsigned int)f2bf(a.x) | ((unsigned int)f2bf(a.y) << 16);
      o.y = (unsigned int)f2bf(a.z) | ((unsigned int)f2bf(a.w) << 16);
      o.z = (unsigned int)f2bf(b.x) | ((unsigned int)f2bf(b.y) << 16);
      o.w = (unsigned int)f2bf(b.z) | ((unsigned int)f2bf(b.w) << 16);
      *(uint4*)(mb + (size_t)j * 8) = o;
    }
  }
}

// ---------------- fused bucket fill for BOTH directions ----------------
// Atomic cost is ~45ns/op device-wide regardless of locality/scope (measured
// r4-r8) -> only atomic COUNT matters (4M). Static XCD-class partition keeps
// plain bucket stores L2-local. bktU entries are ushort (movie id < 64k).
__global__ __launch_bounds__(256) void k_fillb2_x(const int* __restrict__ srcU,
                                                  const int* __restrict__ dstM,
                                                  int* __restrict__ curM,
                                                  int* __restrict__ bktM,
                                                  int* __restrict__ ovfM_cnt,
                                                  int* __restrict__ ovfM,
                                                  int* __restrict__ curU,
                                                  unsigned short* __restrict__ bktU,
                                                  int* __restrict__ ovfU_cnt,
                                                  int* __restrict__ ovfU,
                                                  int E, int NM_, int NU_) {
  int xg = blockIdx.x & 7;
  int mlo = (int)(((long long)NM_ * xg) >> 3);
  int mhi = (xg == 7) ? NM_ : (int)(((long long)NM_ * (xg + 1)) >> 3);
  int ulo = (int)(((long long)NU_ * xg) >> 3);
  int uhi = (xg == 7) ? NU_ : (int)(((long long)NU_ * (xg + 1)) >> 3);
  int li = (blockIdx.x >> 3) * blockDim.x + threadIdx.x;
  int stride = (gridDim.x >> 3) * blockDim.x;
  int E4 = E >> 2;
  const int4* s4 = (const int4*)srcU;
  const int4* d4 = (const int4*)dstM;
  for (int e = li; e < E4; e += stride) {
    int4 d = d4[e];
    int4 s = s4[e];
#pragma unroll
    for (int k = 0; k < 4; ++k) {
      int dd = (k == 0) ? d.x : (k == 1) ? d.y : (k == 2) ? d.z : d.w;
      int ss = (k == 0) ? s.x : (k == 1) ? s.y : (k == 2) ? s.z : s.w;
      if (dd >= mlo && dd < mhi) {
        int p = atomicAdd(&curM[dd], 1);
        if (p < CAP_M) bktM[(size_t)dd * CAP_M + p] = ss;
        else { int q = atomicAdd(ovfM_cnt, 1); if (q < OVF_MAX) { ovfM[2 * q] = dd; ovfM[2 * q + 1] = ss; } }
      }
      if (ss >= ulo && ss < uhi) {
        int p = atomicAdd(&curU[ss], 1);
        if (p < CAP_U) bktU[(size_t)ss * CAP_U + p] = (unsigned short)dd;
        else { int q = atomicAdd(ovfU_cnt, 1); if (q < OVF_MAX) { ovfU[2 * q] = ss; ovfU[2 * q + 1] = dd; } }
      }
    }
  }
  for (int e = E4 * 4 + li; e < E; e += stride) {
    int dd = dstM[e];
    int ss = srcU[e];
    if (dd >= mlo && dd < mhi) {
      int p = atomicAdd(&curM[dd], 1);
      if (p < CAP_M) bktM[(size_t)dd * CAP_M + p] = ss;
      else { int q = atomicAdd(ovfM_cnt, 1); if (q < OVF_MAX) { ovfM[2 * q] = dd; ovfM[2 * q + 1] = ss; } }
    }
    if (ss >= ulo && ss < uhi) {
      int p = atomicAdd(&curU[ss], 1);
      if (p < CAP_U) bktU[(size_t)ss * CAP_U + p] = (unsigned short)dd;
      else { int q = atomicAdd(ovfU_cnt, 1); if (q < OVF_MAX) { ovfU[2 * q] = ss; ovfU[2 * q + 1] = dd; } }
    }
  }
}

// ---------------- aggregation: 8 lanes/node, 16B uint4 loads (r10 proven) ----------------
// Lane q=t&7 holds cols 8q..8q+7 (uint4 = 8 bf16 = 16B). One wave VMEM
// instruction gathers 8 rows. IT = bucket index type (int or ushort).
__device__ __forceinline__ void acc8(float4& a, float4& b, uint4 w) {
  a.x += __uint_as_float(w.x << 16);
  a.y += __uint_as_float(w.x & 0xFFFF0000u);
  a.z += __uint_as_float(w.y << 16);
  a.w += __uint_as_float(w.y & 0xFFFF0000u);
  b.x += __uint_as_float(w.z << 16);
  b.y += __uint_as_float(w.z & 0xFFFF0000u);
  b.z += __uint_as_float(w.w << 16);
  b.w += __uint_as_float(w.w & 0xFFFF0000u);
}

template <typename IT>
__global__ __launch_bounds__(256) void k_agg8(const unsigned short* __restrict__ xb,
                                              const int* __restrict__ cur,
                                              const IT* __restrict__ bkt,
                                              int cap,
                                              float* __restrict__ agg,
                                              int n_dst) {
  int t = threadIdx.x;
  int q = t & 7;                        // col octet: cols 8q..8q+7
  int gg = (blockIdx.x * 256 + t) >> 3; // node
  int stride = (gridDim.x * 256) >> 3;

  for (int node = gg; node < n_dst; node += stride) {
    int deg = cur[node];
    int nb = deg < cap ? deg : cap;
    const IT* lst = bkt + (size_t)node * cap;
    float4 a = make_float4(0.f, 0.f, 0.f, 0.f);
    float4 b = a;
    int e = 0;
    for (; e + 4 <= nb; e += 4) {
      int i0, i1, i2, i3;
      if (sizeof(IT) == 2) {
        ushort4 ia = *(const ushort4*)&lst[e];   // 8B broadcast across group
        i0 = ia.x; i1 = ia.y; i2 = ia.z; i3 = ia.w;
      } else {
        int4 ia = *(const int4*)&lst[e];         // 16B broadcast across group
        i0 = ia.x; i1 = ia.y; i2 = ia.z; i3 = ia.w;
      }
      uint4 w0 = *(const uint4*)&xb[(size_t)i0 * HDIM + 8 * q];
      uint4 w1 = *(const uint4*)&xb[(size_t)i1 * HDIM + 8 * q];
      uint4 w2 = *(const uint4*)&xb[(size_t)i2 * HDIM + 8 * q];
      uint4 w3 = *(const uint4*)&xb[(size_t)i3 * HDIM + 8 * q];
      acc8(a, b, w0);
      acc8(a, b, w1);
      acc8(a, b, w2);
      acc8(a, b, w3);
    }
    for (; e < nb; ++e) {
      uint4 w0 = *(const uint4*)&xb[(size_t)lst[e] * HDIM + 8 * q];
      acc8(a, b, w0);
    }
    float inv = deg > 0 ? 1.f / (float)deg : 0.f;
    a.x *= inv; a.y *= inv; a.z *= inv; a.w *= inv;
    b.x *= inv; b.y *= inv; b.z *= inv; b.w *= inv;
    *(float4*)&agg[(size_t)node * HDIM + 8 * q] = a;
    *(float4*)&agg[(size_t)node * HDIM + 8 * q + 4] = b;
  }
}

// ---------------- overflow fixup (combined; normally a no-op) ----------------
__device__ __forceinline__ void fix_body(const int* __restrict__ cnt_p,
                                         const int* __restrict__ ovf,
                                         const unsigned short* __restrict__ xb,
                                         const int* __restrict__ cur,
                                         float* __restrict__ agg,
                                         int bid, int nblk) {
  int n = *cnt_p;
  if (n > OVF_MAX) n = OVF_MAX;
  int tid = bid * 256 + threadIdx.x;
  int q = tid & 15;
  int p = tid >> 4;
  int stride = (nblk * 256) >> 4;
  for (; p < n; p += stride) {
    int d = ovf[2 * p];
    int s = ovf[2 * p + 1];
    float inv = 1.f / (float)cur[d];
    ushort4 v = *(const ushort4*)&xb[(size_t)s * HDIM + 4 * q];
    atomicAdd(&agg[(size_t)d * HDIM + 4 * q + 0], bf2f(v.x) * inv);
    atomicAdd(&agg[(size_t)d * HDIM + 4 * q + 1], bf2f(v.y) * inv);
    atomicAdd(&agg[(size_t)d * HDIM + 4 * q + 2], bf2f(v.z) * inv);
    atomicAdd(&agg[(size_t)d * HDIM + 4 * q + 3], bf2f(v.w) * inv);
  }
}

__global__ __launch_bounds__(256) void k_fix2(const int* __restrict__ cntM,
                                              const int* __restrict__ ovfM,
                                              const unsigned short* __restrict__ xbM,
                                              const int* __restrict__ curM,
                                              float* __restrict__ aggM,
                                              const int* __restrict__ cntU,
                                              const int* __restrict__ ovfU,
                                              const unsigned short* __restrict__ xbU,
                                              const int* __restrict__ curU,
                                              float* __restrict__ aggU) {
  if (blockIdx.x < 16) fix_body(cntM, ovfM, xbM, curM, aggM, blockIdx.x, 16);
  else                 fix_body(cntU, ovfU, xbU, curU, aggU, blockIdx.x - 16, 16);
}

// component select with compile-time c (folds under #pragma unroll)
__device__ __forceinline__ float f4c(const float4& v, int c) {
  return c == 0 ? v.x : c == 1 ? v.y : c == 2 ? v.z : v.w;
}

// ---------------- transform: out = A@Wl + X@Wr + b (opt relu) ----------------
// 8 nodes per 64-lane wave (2 per 16-lane group). h rows split across groups;
// partials butterfly-reduced over groups. W read from LDS once per 8 nodes.
// X is bf16; X/out (and A/out) may ALIAS (in-place per-row).
template <int OUTBF>
__global__ __launch_bounds__(256) void k_xform(const float* A,
                                               const unsigned short* X,
                                               const float* __restrict__ Wl,
                                               const float* __restrict__ Wr,
                                               const float* __restrict__ bias,
                                               void* outv,
                                               int n_dst, int do_relu) {
  __shared__ float sW[2 * HDIM * HDIM];    // Wl | Wr, 32 KB
  __shared__ float sAX[4][2][8][HDIM];     // [wave][a|x][slot][col], 16 KB

  int t = threadIdx.x;
  {
    const float4* wl4 = (const float4*)Wl;
    const float4* wr4 = (const float4*)Wr;
    float4* s4 = (float4*)sW;
    for (int i = t; i < HDIM * HDIM / 4; i += 256) {
      s4[i] = wl4[i];
      s4[HDIM * HDIM / 4 + i] = wr4[i];
    }
  }
  __syncthreads();

  int lane = t & 63;
  int w = t >> 6;
  int q = lane & 15;
  int g = lane >> 4;
  float4 bj = *(const float4*)&bias[4 * q];

  int wid = blockIdx.x * 4 + w;
  int nw = gridDim.x * 4;

  for (int base = 8 * wid; base < n_dst; base += 8 * nw) {
    int na = base + g;
    int nb = base + 4 + g;
    float4 z = make_float4(0.f, 0.f, 0.f, 0.f);
    float4 aA = z, xA = z, aB = z, xB = z;
    if (na < n_dst) {
      aA = *(const float4*)&A[(size_t)na * HDIM + 4 * q];
      ushort4 v = *(const ushort4*)&X[(size_t)na * HDIM + 4 * q];
      xA = make_float4(bf2f(v.x), bf2f(v.y), bf2f(v.z), bf2f(v.w));
    }
    if (nb < n_dst) {
      aB = *(const float4*)&A[(size_t)nb * HDIM + 4 * q];
      ushort4 v = *(const ushort4*)&X[(size_t)nb * HDIM + 4 * q];
      xB = make_float4(bf2f(v.x), bf2f(v.y), bf2f(v.z), bf2f(v.w));
    }
    *(float4*)&sAX[w][0][g][4 * q] = aA;
    *(float4*)&sAX[w][1][g][4 * q] = xA;
    *(float4*)&sAX[w][0][4 + g][4 * q] = aB;
    *(float4*)&sAX[w][1][4 + g][4 * q] = xB;

    float4 o[8];
#pragma unroll
    for (int s = 0; s < 8; ++s) o[s] = z;

#pragma unroll
    for (int hq = 0; hq < 4; ++hq) {
      int hbase = 16 * g + 4 * hq;
      float4 wl[4], wr[4];
#pragma unroll
      for (int c = 0; c < 4; ++c) {
        wl[c] = *(const float4*)&sW[(hbase + c) * HDIM + 4 * q];
        wr[c] = *(const float4*)&sW[HDIM * HDIM + (hbase + c) * HDIM + 4 * q];
      }
#pragma unroll
      for (int s = 0; s < 8; ++s) {
        float4 av = *(const float4*)&sAX[w][0][s][hbase];
        float4 xv = *(const float4*)&sAX[w][1][s][hbase];
#pragma unroll
        for (int c = 0; c < 4; ++c) {
          float a1 = f4c(av, c), x1 = f4c(xv, c);
          o[s].x += a1 * wl[c].x + x1 * wr[c].x;
          o[s].y += a1 * wl[c].y + x1 * wr[c].y;
          o[s].z += a1 * wl[c].z + x1 * wr[c].z;
          o[s].w += a1 * wl[c].w + x1 * wr[c].w;
        }
      }
    }

#pragma unroll
    for (int m = 16; m <= 32; m <<= 1) {
#pragma unroll
      for (int s = 0; s < 8; ++s) {
        o[s].x += __shfl_xor(o[s].x, m);
        o[s].y += __shfl_xor(o[s].y, m);
        o[s].z += __shfl_xor(o[s].z, m);
        o[s].w += __shfl_xor(o[s].w, m);
      }
    }

    float4 s0, s1;
    if (g == 0)      { s0 = o[0]; s1 = o[1]; }
    else if (g == 1) { s0 = o[2]; s1 = o[3]; }
    else if (g == 2) { s0 = o[4]; s1 = o[5]; }
    else             { s0 = o[6]; s1 = o[7]; }
    int n0 = base + 2 * g;
    int n1 = base + 2 * g + 1;
    s0.x += bj.x; s0.y += bj.y; s0.z += bj.z; s0.w += bj.w;
    s1.x += bj.x; s1.y += bj.y; s1.z += bj.z; s1.w += bj.w;
    if (do_relu) {
      s0.x = fmaxf(s0.x, 0.f); s0.y = fmaxf(s0.y, 0.f);
      s0.z = fmaxf(s0.z, 0.f); s0.w = fmaxf(s0.w, 0.f);
      s1.x = fmaxf(s1.x, 0.f); s1.y = fmaxf(s1.y, 0.f);
      s1.z = fmaxf(s1.z, 0.f); s1.w = fmaxf(s1.w, 0.f);
    }
    if (OUTBF) {
      unsigned short* ob = (unsigned short*)outv;
      if (n0 < n_dst) {
        ushort4 r = make_ushort4(f2bf(s0.x), f2bf(s0.y), f2bf(s0.z), f2bf(s0.w));
        *(ushort4*)&ob[(size_t)n0 * HDIM + 4 * q] = r;
      }
      if (n1 < n_dst) {
        ushort4 r = make_ushort4(f2bf(s1.x), f2bf(s1.y), f2bf(s1.z), f2bf(s1.w));
        *(ushort4*)&ob[(size_t)n1 * HDIM + 4 * q] = r;
      }
    } else {
      float* of = (float*)outv;
      if (n0 < n_dst) *(float4*)&of[(size_t)n0 * HDIM + 4 * q] = s0;
      if (n1 < n_dst) *(float4*)&of[(size_t)n1 * HDIM + 4 * q] = s1;
    }
  }
}

// ---------------- launch ----------------

static inline int imin(int a, int b) { return a < b ? a : b; }

extern "C" void kernel_launch(void* const* d_in, const int* in_sizes, int n_in,
                              void* d_out, int out_size, void* d_ws, size_t ws_size,
                              hipStream_t stream) {
  const int NU = in_sizes[0];
  const int NM = in_sizes[1];
  const int E  = in_sizes[2];

  const int* src_um = (const int*)d_in[2];
  const int* dst_um = (const int*)d_in[3];
  const float* user_table  = (const float*)d_in[6];
  const float* movie_table = (const float*)d_in[7];
  const float* Wl1_um = (const float*)d_in[8];
  const float* Wr1_um = (const float*)d_in[9];
  const float* Wl1_mu = (const float*)d_in[10];
  const float* Wr1_mu = (const float*)d_in[11];
  const float* Wl2_um = (const float*)d_in[12];
  const float* Wr2_um = (const float*)d_in[13];
  const float* Wl2_mu = (const float*)d_in[14];
  const float* Wr2_mu = (const float*)d_in[15];
  const float* b1_um = (const float*)d_in[16];
  const float* b1_mu = (const float*)d_in[17];
  const float* b2_um = (const float*)d_in[18];
  const float* b2_mu = (const float*)d_in[19];

  float* out_u2 = (float*)d_out;                       // [NU,64]
  float* out_m2 = (float*)d_out + (size_t)NU * HDIM;   // [NM,64]
  float* aggu = out_u2;   // agg scratch in d_out; layer2 xform is per-row in-place
  float* aggm = out_m2;

  // workspace carve (256B aligned); total ~61 MB
  char* ws = (char*)d_ws;
  size_t off = 0;
  auto carve = [&](size_t bytes) -> char* {
    char* p = ws + off;
    off = (off + bytes + 255) & ~(size_t)255;
    return p;
  };
  int* meta = (int*)carve((size_t)(NM + NU + 2) * 4);
  int* curm = meta;
  int* curu = meta + NM;
  int* ovfm_cnt = meta + NM + NU;
  int* ovfu_cnt = meta + NM + NU + 1;
  int nmeta = NM + NU + 2;
  int* ovfm = (int*)carve((size_t)OVF_MAX * 2 * 4);
  int* ovfu = (int*)carve((size_t)OVF_MAX * 2 * 4);
  int* bktm = (int*)carve((size_t)NM * CAP_M * 4);                    // user ids (int)
  unsigned short* bktu = (unsigned short*)carve((size_t)NU * CAP_U * 2);  // movie ids (ushort)
  unsigned short* mb = (unsigned short*)carve((size_t)NM * HDIM * 2);  // bf16 movie tbl -> m1
  unsigned short* ub = (unsigned short*)carve((size_t)NU * HDIM * 2);  // bf16 user tbl -> u1
  (void)ws_size;

  const int TB = 256;

  // 0) init: zero counters + bf16 table copies (one streaming dispatch)
  int n8u = NU * HDIM / 8, n8m = NM * HDIM / 8;
  k_init<<<3072, TB, 0, stream>>>(meta, nmeta, user_table, ub, n8u,
                                  movie_table, mb, n8m);

  // 1) fused bucket fill (static XCD-class partition, r7/r10 proven)
  k_fillb2_x<<<2048, TB, 0, stream>>>(src_um, dst_um,
                                      curm, bktm, ovfm_cnt, ovfm,
                                      curu, bktu, ovfu_cnt, ovfu,
                                      E, NM, NU);

  // agg grids: 8 lanes/node -> 32 nodes/block
  int gAm = imin((NM + 31) / 32, 8192);
  int gAu = imin((NU + 31) / 32, 8192);
  int gXm = imin((NM + 31) / 32, 1024);
  int gXu = imin((NU + 31) / 32, 1024);

  // 2) layer 1 (relu): SERIAL aggs (r9 cache-mixing lesson), fix, serial xforms
  k_agg8<int><<<gAm, TB, 0, stream>>>(ub, curm, bktm, CAP_M, aggm, NM);
  k_agg8<unsigned short><<<gAu, TB, 0, stream>>>(mb, curu, bktu, CAP_U, aggu, NU);
  k_fix2<<<32, TB, 0, stream>>>(ovfm_cnt, ovfm, ub, curm, aggm,
                                ovfu_cnt, ovfu, mb, curu, aggu);
  k_xform<1><<<gXm, TB, 0, stream>>>(aggm, mb, Wl1_um, Wr1_um, b1_um,
                                     mb, NM, 1);   // mb becomes m1 (bf16)
  k_xform<1><<<gXu, TB, 0, stream>>>(aggu, ub, Wl1_mu, Wr1_mu, b1_mu,
                                     ub, NU, 1);   // ub becomes u1 (bf16)

  // 3) layer 2 (no relu): same shape, outputs to d_out (in-place over agg rows)
  k_agg8<int><<<gAm, TB, 0, stream>>>(ub, curm, bktm, CAP_M, aggm, NM);
  k_agg8<unsigned short><<<gAu, TB, 0, stream>>>(mb, curu, bktu, CAP_U, aggu, NU);
  k_fix2<<<32, TB, 0, stream>>>(ovfm_cnt, ovfm, ub, curm, aggm,
                                ovfu_cnt, ovfu, mb, curu, aggu);
  k_xform<0><<<gXm, TB, 0, stream>>>(aggm, mb, Wl2_um, Wr2_um, b2_um,
                                     out_m2, NM, 0);
  k_xform<0><<<gXu, TB, 0, stream>>>(aggu, ub, Wl2_mu, Wr2_mu, b2_mu,
                                     out_u2, NU, 0);
}

// Round 13
// 420.175 us; speedup vs baseline: 1.4904x; 1.2452x over previous
//
#include <hip/hip_runtime.h>

#define HDIM 64
#define CAP_M 96
#define CAP_U 32
#define OVF_MAX 65536

typedef __attribute__((ext_vector_type(8))) short bf16x8;   // 8 bf16 (4 VGPRs)
typedef __attribute__((ext_vector_type(4))) float f32x4;    // 4 fp32

// ---------------- bf16 helpers ----------------
__device__ __forceinline__ float bf2f(unsigned short u) {
  unsigned int x = ((unsigned int)u) << 16;
  return __uint_as_float(x);
}
__device__ __forceinline__ unsigned short f2bf(float f) {
  unsigned int x = __float_as_uint(f);
  unsigned int r = (x + 0x7FFFu + ((x >> 16) & 1u)) >> 16;  // RNE
  return (unsigned short)r;
}

// ---------------- init: zero meta + bf16 table copies (one dispatch) ----------------
__global__ __launch_bounds__(256) void k_init(int* __restrict__ meta, int nmeta,
                                              const float* __restrict__ ut,
                                              unsigned short* __restrict__ ub, int n8u,
                                              const float* __restrict__ mt,
                                              unsigned short* __restrict__ mb, int n8m) {
  int bid = blockIdx.x;
  if (bid < 512) {
    int i = bid * 256 + threadIdx.x;
    for (int j = i; j < nmeta; j += 512 * 256) meta[j] = 0;
  } else if (bid < 512 + 2048) {
    int i = (bid - 512) * 256 + threadIdx.x;
    for (int j = i; j < n8u; j += 2048 * 256) {
      const float4* p = (const float4*)(ut + (size_t)j * 8);
      float4 a = p[0], b = p[1];
      uint4 o;
      o.x = (unsigned int)f2bf(a.x) | ((unsigned int)f2bf(a.y) << 16);
      o.y = (unsigned int)f2bf(a.z) | ((unsigned int)f2bf(a.w) << 16);
      o.z = (unsigned int)f2bf(b.x) | ((unsigned int)f2bf(b.y) << 16);
      o.w = (unsigned int)f2bf(b.z) | ((unsigned int)f2bf(b.w) << 16);
      *(uint4*)(ub + (size_t)j * 8) = o;
    }
  } else {
    int i = (bid - 512 - 2048) * 256 + threadIdx.x;
    for (int j = i; j < n8m; j += 512 * 256) {
      const float4* p = (const float4*)(mt + (size_t)j * 8);
      float4 a = p[0], b = p[1];
      uint4 o;
      o.x = (unsigned int)f2bf(a.x) | ((unsigned int)f2bf(a.y) << 16);
      o.y = (unsigned int)f2bf(a.z) | ((unsigned int)f2bf(a.w) << 16);
      o.z = (unsigned int)f2bf(b.x) | ((unsigned int)f2bf(b.y) << 16);
      o.w = (unsigned int)f2bf(b.z) | ((unsigned int)f2bf(b.w) << 16);
      *(uint4*)(mb + (size_t)j * 8) = o;
    }
  }
}

// ---------------- fused bucket fill (r7/r12 proven; atomic-floor ~172us) ----------------
__global__ __launch_bounds__(256) void k_fillb2_x(const int* __restrict__ srcU,
                                                  const int* __restrict__ dstM,
                                                  int* __restrict__ curM,
                                                  int* __restrict__ bktM,
                                                  int* __restrict__ ovfM_cnt,
                                                  int* __restrict__ ovfM,
                                                  int* __restrict__ curU,
                                                  unsigned short* __restrict__ bktU,
                                                  int* __restrict__ ovfU_cnt,
                                                  int* __restrict__ ovfU,
                                                  int E, int NM_, int NU_) {
  int xg = blockIdx.x & 7;
  int mlo = (int)(((long long)NM_ * xg) >> 3);
  int mhi = (xg == 7) ? NM_ : (int)(((long long)NM_ * (xg + 1)) >> 3);
  int ulo = (int)(((long long)NU_ * xg) >> 3);
  int uhi = (xg == 7) ? NU_ : (int)(((long long)NU_ * (xg + 1)) >> 3);
  int li = (blockIdx.x >> 3) * blockDim.x + threadIdx.x;
  int stride = (gridDim.x >> 3) * blockDim.x;
  int E4 = E >> 2;
  const int4* s4 = (const int4*)srcU;
  const int4* d4 = (const int4*)dstM;
  for (int e = li; e < E4; e += stride) {
    int4 d = d4[e];
    int4 s = s4[e];
#pragma unroll
    for (int k = 0; k < 4; ++k) {
      int dd = (k == 0) ? d.x : (k == 1) ? d.y : (k == 2) ? d.z : d.w;
      int ss = (k == 0) ? s.x : (k == 1) ? s.y : (k == 2) ? s.z : s.w;
      if (dd >= mlo && dd < mhi) {
        int p = atomicAdd(&curM[dd], 1);
        if (p < CAP_M) bktM[(size_t)dd * CAP_M + p] = ss;
        else { int q = atomicAdd(ovfM_cnt, 1); if (q < OVF_MAX) { ovfM[2 * q] = dd; ovfM[2 * q + 1] = ss; } }
      }
      if (ss >= ulo && ss < uhi) {
        int p = atomicAdd(&curU[ss], 1);
        if (p < CAP_U) bktU[(size_t)ss * CAP_U + p] = (unsigned short)dd;
        else { int q = atomicAdd(ovfU_cnt, 1); if (q < OVF_MAX) { ovfU[2 * q] = ss; ovfU[2 * q + 1] = dd; } }
      }
    }
  }
  for (int e = E4 * 4 + li; e < E; e += stride) {
    int dd = dstM[e];
    int ss = srcU[e];
    if (dd >= mlo && dd < mhi) {
      int p = atomicAdd(&curM[dd], 1);
      if (p < CAP_M) bktM[(size_t)dd * CAP_M + p] = ss;
      else { int q = atomicAdd(ovfM_cnt, 1); if (q < OVF_MAX) { ovfM[2 * q] = dd; ovfM[2 * q + 1] = ss; } }
    }
    if (ss >= ulo && ss < uhi) {
      int p = atomicAdd(&curU[ss], 1);
      if (p < CAP_U) bktU[(size_t)ss * CAP_U + p] = (unsigned short)dd;
      else { int q = atomicAdd(ovfU_cnt, 1); if (q < OVF_MAX) { ovfU[2 * q] = ss; ovfU[2 * q + 1] = dd; } }
    }
  }
}

// ---------------- aggregation: 8 lanes/node, 16B uint4 loads (r10 proven) ----------------
__device__ __forceinline__ void acc8(float4& a, float4& b, uint4 w) {
  a.x += __uint_as_float(w.x << 16);
  a.y += __uint_as_float(w.x & 0xFFFF0000u);
  a.z += __uint_as_float(w.y << 16);
  a.w += __uint_as_float(w.y & 0xFFFF0000u);
  b.x += __uint_as_float(w.z << 16);
  b.y += __uint_as_float(w.z & 0xFFFF0000u);
  b.z += __uint_as_float(w.w << 16);
  b.w += __uint_as_float(w.w & 0xFFFF0000u);
}

template <typename IT>
__global__ __launch_bounds__(256) void k_agg8(const unsigned short* __restrict__ xb,
                                              const int* __restrict__ cur,
                                              const IT* __restrict__ bkt,
                                              int cap,
                                              float* __restrict__ agg,
                                              int n_dst) {
  int t = threadIdx.x;
  int q = t & 7;
  int gg = (blockIdx.x * 256 + t) >> 3;
  int stride = (gridDim.x * 256) >> 3;

  for (int node = gg; node < n_dst; node += stride) {
    int deg = cur[node];
    int nb = deg < cap ? deg : cap;
    const IT* lst = bkt + (size_t)node * cap;
    float4 a = make_float4(0.f, 0.f, 0.f, 0.f);
    float4 b = a;
    int e = 0;
    for (; e + 4 <= nb; e += 4) {
      int i0, i1, i2, i3;
      if (sizeof(IT) == 2) {
        ushort4 ia = *(const ushort4*)&lst[e];
        i0 = ia.x; i1 = ia.y; i2 = ia.z; i3 = ia.w;
      } else {
        int4 ia = *(const int4*)&lst[e];
        i0 = ia.x; i1 = ia.y; i2 = ia.z; i3 = ia.w;
      }
      uint4 w0 = *(const uint4*)&xb[(size_t)i0 * HDIM + 8 * q];
      uint4 w1 = *(const uint4*)&xb[(size_t)i1 * HDIM + 8 * q];
      uint4 w2 = *(const uint4*)&xb[(size_t)i2 * HDIM + 8 * q];
      uint4 w3 = *(const uint4*)&xb[(size_t)i3 * HDIM + 8 * q];
      acc8(a, b, w0);
      acc8(a, b, w1);
      acc8(a, b, w2);
      acc8(a, b, w3);
    }
    for (; e < nb; ++e) {
      uint4 w0 = *(const uint4*)&xb[(size_t)lst[e] * HDIM + 8 * q];
      acc8(a, b, w0);
    }
    float inv = deg > 0 ? 1.f / (float)deg : 0.f;
    a.x *= inv; a.y *= inv; a.z *= inv; a.w *= inv;
    b.x *= inv; b.y *= inv; b.z *= inv; b.w *= inv;
    *(float4*)&agg[(size_t)node * HDIM + 8 * q] = a;
    *(float4*)&agg[(size_t)node * HDIM + 8 * q + 4] = b;
  }
}

// ---------------- overflow fixup (combined; normally a no-op) ----------------
__device__ __forceinline__ void fix_body(const int* __restrict__ cnt_p,
                                         const int* __restrict__ ovf,
                                         const unsigned short* __restrict__ xb,
                                         const int* __restrict__ cur,
                                         float* __restrict__ agg,
                                         int bid, int nblk) {
  int n = *cnt_p;
  if (n > OVF_MAX) n = OVF_MAX;
  int tid = bid * 256 + threadIdx.x;
  int q = tid & 15;
  int p = tid >> 4;
  int stride = (nblk * 256) >> 4;
  for (; p < n; p += stride) {
    int d = ovf[2 * p];
    int s = ovf[2 * p + 1];
    float inv = 1.f / (float)cur[d];
    ushort4 v = *(const ushort4*)&xb[(size_t)s * HDIM + 4 * q];
    atomicAdd(&agg[(size_t)d * HDIM + 4 * q + 0], bf2f(v.x) * inv);
    atomicAdd(&agg[(size_t)d * HDIM + 4 * q + 1], bf2f(v.y) * inv);
    atomicAdd(&agg[(size_t)d * HDIM + 4 * q + 2], bf2f(v.z) * inv);
    atomicAdd(&agg[(size_t)d * HDIM + 4 * q + 3], bf2f(v.w) * inv);
  }
}

__global__ __launch_bounds__(256) void k_fix2(const int* __restrict__ cntM,
                                              const int* __restrict__ ovfM,
                                              const unsigned short* __restrict__ xbM,
                                              const int* __restrict__ curM,
                                              float* __restrict__ aggM,
                                              const int* __restrict__ cntU,
                                              const int* __restrict__ ovfU,
                                              const unsigned short* __restrict__ xbU,
                                              const int* __restrict__ curU,
                                              float* __restrict__ aggU) {
  if (blockIdx.x < 16) fix_body(cntM, ovfM, xbM, curM, aggM, blockIdx.x, 16);
  else                 fix_body(cntU, ovfU, xbU, curU, aggU, blockIdx.x - 16, 16);
}

// ---------------- MFMA transform: out = [agg|X] @ [Wl;Wr] + b (opt relu) ----------------
// One wave = 16 nodes (M=16). K=128 in 4 steps of 32; N=64 in 4 tiles of 16.
// A-frag: lane l holds IN[nbase+(l&15)][32s + 8*(l>>4) + j], j=0..7.
//   s=0,1 from agg (fp32, cvt->bf16); s=2,3 from X (bf16 16B load).
// B-frag: lane l holds W[32s+8*(l>>4)+j][16n+(l&15)] = sWt[col][k] (16B LDS read,
//   W^T staged bf16, row stride 136 shorts -> <=2-way banks).
// C/D mapping (m89-verified): col = lane&15, row = (lane>>4)*4 + reg.
// Store staged through LDS for coalescing. X/out and A/out may alias
// (same-tile rows read before stored, per-wave program order).
template <int OUTBF>
__global__ __launch_bounds__(256) void k_xmfma(const float* A,
                                               const unsigned short* X,
                                               const float* __restrict__ Wl,
                                               const float* __restrict__ Wr,
                                               const float* __restrict__ bias,
                                               void* outv,
                                               int n_dst, int do_relu) {
  __shared__ unsigned short sWt[64][136];  // W^T bf16, padded: 17408 B
  __shared__ float sOut[4][16][68];        // per-wave C staging: 17408 B

  int t = threadIdx.x;
  for (int id = t; id < 64 * 128; id += 256) {
    int col = id & 63;
    int k = id >> 6;
    float wv = (k < 64) ? Wl[k * 64 + col] : Wr[(k - 64) * 64 + col];
    sWt[col][k] = f2bf(wv);
  }
  __syncthreads();

  int w = t >> 6;
  int l = t & 63;
  int lm = l & 15;   // M row within tile / N col within tile
  int lg = l >> 4;   // k-octet group
  int wid = blockIdx.x * 4 + w;
  int nw = gridDim.x * 4;
  int ntiles = (n_dst + 15) >> 4;

  for (int tile = wid; tile < ntiles; tile += nw) {
    int nbase = tile << 4;
    int row = nbase + lm;
    int rowc = row < n_dst ? row : (n_dst - 1);

    // ---- A fragments ----
    bf16x8 afr[4];
    const float* ar = A + (size_t)rowc * HDIM;
#pragma unroll
    for (int s = 0; s < 2; ++s) {
      float4 f0 = *(const float4*)(ar + 32 * s + 8 * lg);
      float4 f1 = *(const float4*)(ar + 32 * s + 8 * lg + 4);
      bf16x8 v;
      v[0] = (short)f2bf(f0.x); v[1] = (short)f2bf(f0.y);
      v[2] = (short)f2bf(f0.z); v[3] = (short)f2bf(f0.w);
      v[4] = (short)f2bf(f1.x); v[5] = (short)f2bf(f1.y);
      v[6] = (short)f2bf(f1.z); v[7] = (short)f2bf(f1.w);
      afr[s] = v;
    }
    const unsigned short* xr = X + (size_t)rowc * HDIM;
#pragma unroll
    for (int s = 0; s < 2; ++s) {
      afr[2 + s] = *(const bf16x8*)(xr + 32 * s + 8 * lg);
    }

    // ---- MFMA: 4 N-tiles x 4 K-steps ----
    f32x4 zz = {0.f, 0.f, 0.f, 0.f};
    f32x4 acc[4];
#pragma unroll
    for (int n = 0; n < 4; ++n) acc[n] = zz;
#pragma unroll
    for (int s = 0; s < 4; ++s) {
#pragma unroll
      for (int n = 0; n < 4; ++n) {
        bf16x8 bfr = *(const bf16x8*)(&sWt[16 * n + lm][32 * s + 8 * lg]);
        acc[n] = __builtin_amdgcn_mfma_f32_16x16x32_bf16(afr[s], bfr, acc[n], 0, 0, 0);
      }
    }

    // ---- bias + relu, stage C to LDS (2-way banks via 68-pad) ----
#pragma unroll
    for (int n = 0; n < 4; ++n) {
      float bj = bias[16 * n + lm];
#pragma unroll
      for (int r = 0; r < 4; ++r) {
        float v = acc[n][r] + bj;
        if (do_relu) v = fmaxf(v, 0.f);
        sOut[w][lg * 4 + r][16 * n + lm] = v;
      }
    }
    // same-wave LDS producer/consumer: compiler inserts lgkmcnt waits

    // ---- coalesced store: lane covers node l>>2, cols (l&3)*16.. ----
    int node = nbase + (l >> 2);
    if (node < n_dst) {
      int c0 = (l & 3) * 16;
      float4 o0 = *(const float4*)&sOut[w][l >> 2][c0];
      float4 o1 = *(const float4*)&sOut[w][l >> 2][c0 + 4];
      float4 o2 = *(const float4*)&sOut[w][l >> 2][c0 + 8];
      float4 o3 = *(const float4*)&sOut[w][l >> 2][c0 + 12];
      if (OUTBF) {
        unsigned short* ob = (unsigned short*)outv;
        uint4 p0, p1;
        p0.x = (unsigned int)f2bf(o0.x) | ((unsigned int)f2bf(o0.y) << 16);
        p0.y = (unsigned int)f2bf(o0.z) | ((unsigned int)f2bf(o0.w) << 16);
        p0.z = (unsigned int)f2bf(o1.x) | ((unsigned int)f2bf(o1.y) << 16);
        p0.w = (unsigned int)f2bf(o1.z) | ((unsigned int)f2bf(o1.w) << 16);
        p1.x = (unsigned int)f2bf(o2.x) | ((unsigned int)f2bf(o2.y) << 16);
        p1.y = (unsigned int)f2bf(o2.z) | ((unsigned int)f2bf(o2.w) << 16);
        p1.z = (unsigned int)f2bf(o3.x) | ((unsigned int)f2bf(o3.y) << 16);
        p1.w = (unsigned int)f2bf(o3.z) | ((unsigned int)f2bf(o3.w) << 16);
        *(uint4*)&ob[(size_t)node * HDIM + c0] = p0;
        *(uint4*)&ob[(size_t)node * HDIM + c0 + 8] = p1;
      } else {
        float* of = (float*)outv;
        *(float4*)&of[(size_t)node * HDIM + c0] = o0;
        *(float4*)&of[(size_t)node * HDIM + c0 + 4] = o1;
        *(float4*)&of[(size_t)node * HDIM + c0 + 8] = o2;
        *(float4*)&of[(size_t)node * HDIM + c0 + 12] = o3;
      }
    }
  }
}

// ---------------- launch ----------------

static inline int imin(int a, int b) { return a < b ? a : b; }

extern "C" void kernel_launch(void* const* d_in, const int* in_sizes, int n_in,
                              void* d_out, int out_size, void* d_ws, size_t ws_size,
                              hipStream_t stream) {
  const int NU = in_sizes[0];
  const int NM = in_sizes[1];
  const int E  = in_sizes[2];

  const int* src_um = (const int*)d_in[2];
  const int* dst_um = (const int*)d_in[3];
  const float* user_table  = (const float*)d_in[6];
  const float* movie_table = (const float*)d_in[7];
  const float* Wl1_um = (const float*)d_in[8];
  const float* Wr1_um = (const float*)d_in[9];
  const float* Wl1_mu = (const float*)d_in[10];
  const float* Wr1_mu = (const float*)d_in[11];
  const float* Wl2_um = (const float*)d_in[12];
  const float* Wr2_um = (const float*)d_in[13];
  const float* Wl2_mu = (const float*)d_in[14];
  const float* Wr2_mu = (const float*)d_in[15];
  const float* b1_um = (const float*)d_in[16];
  const float* b1_mu = (const float*)d_in[17];
  const float* b2_um = (const float*)d_in[18];
  const float* b2_mu = (const float*)d_in[19];

  float* out_u2 = (float*)d_out;                       // [NU,64]
  float* out_m2 = (float*)d_out + (size_t)NU * HDIM;   // [NM,64]
  float* aggu = out_u2;   // agg scratch in d_out; layer2 xform in-place per-row
  float* aggm = out_m2;

  // workspace carve (256B aligned); total ~61 MB
  char* ws = (char*)d_ws;
  size_t off = 0;
  auto carve = [&](size_t bytes) -> char* {
    char* p = ws + off;
    off = (off + bytes + 255) & ~(size_t)255;
    return p;
  };
  int* meta = (int*)carve((size_t)(NM + NU + 2) * 4);
  int* curm = meta;
  int* curu = meta + NM;
  int* ovfm_cnt = meta + NM + NU;
  int* ovfu_cnt = meta + NM + NU + 1;
  int nmeta = NM + NU + 2;
  int* ovfm = (int*)carve((size_t)OVF_MAX * 2 * 4);
  int* ovfu = (int*)carve((size_t)OVF_MAX * 2 * 4);
  int* bktm = (int*)carve((size_t)NM * CAP_M * 4);                        // user ids (int)
  unsigned short* bktu = (unsigned short*)carve((size_t)NU * CAP_U * 2);  // movie ids (ushort)
  unsigned short* mb = (unsigned short*)carve((size_t)NM * HDIM * 2);     // bf16 movie tbl -> m1
  unsigned short* ub = (unsigned short*)carve((size_t)NU * HDIM * 2);     // bf16 user tbl -> u1
  (void)ws_size;

  const int TB = 256;

  // 0) init: zero counters + bf16 table copies (one streaming dispatch)
  int n8u = NU * HDIM / 8, n8m = NM * HDIM / 8;
  k_init<<<3072, TB, 0, stream>>>(meta, nmeta, user_table, ub, n8u,
                                  movie_table, mb, n8m);

  // 1) fused bucket fill
  k_fillb2_x<<<2048, TB, 0, stream>>>(src_um, dst_um,
                                      curm, bktm, ovfm_cnt, ovfm,
                                      curu, bktu, ovfu_cnt, ovfu,
                                      E, NM, NU);

  int gAm = imin((NM + 31) / 32, 8192);
  int gAu = imin((NU + 31) / 32, 8192);
  int gXm = (NM + 63) / 64;   // 64 nodes/block (4 waves x 16)
  int gXu = (NU + 63) / 64;

  // 2) layer 1 (relu): serial aggs (r9 lesson), fix, MFMA xforms (in-place bf16)
  k_agg8<int><<<gAm, TB, 0, stream>>>(ub, curm, bktm, CAP_M, aggm, NM);
  k_agg8<unsigned short><<<gAu, TB, 0, stream>>>(mb, curu, bktu, CAP_U, aggu, NU);
  k_fix2<<<32, TB, 0, stream>>>(ovfm_cnt, ovfm, ub, curm, aggm,
                                ovfu_cnt, ovfu, mb, curu, aggu);
  k_xmfma<1><<<gXm, TB, 0, stream>>>(aggm, mb, Wl1_um, Wr1_um, b1_um,
                                     mb, NM, 1);   // mb becomes m1 (bf16)
  k_xmfma<1><<<gXu, TB, 0, stream>>>(aggu, ub, Wl1_mu, Wr1_mu, b1_mu,
                                     ub, NU, 1);   // ub becomes u1 (bf16)

  // 3) layer 2 (no relu): aggs into d_out, MFMA xforms in-place -> fp32 out
  k_agg8<int><<<gAm, TB, 0, stream>>>(ub, curm, bktm, CAP_M, aggm, NM);
  k_agg8<unsigned short><<<gAu, TB, 0, stream>>>(mb, curu, bktu, CAP_U, aggu, NU);
  k_fix2<<<32, TB, 0, stream>>>(ovfm_cnt, ovfm, ub, curm, aggm,
                                ovfu_cnt, ovfu, mb, curu, aggu);
  k_xmfma<0><<<gXm, TB, 0, stream>>>(aggm, mb, Wl2_um, Wr2_um, b2_um,
                                     out_m2, NM, 0);
  k_xmfma<0><<<gXu, TB, 0, stream>>>(aggu, ub, Wl2_mu, Wr2_mu, b2_mu,
                                     out_u2, NU, 0);
}